// Round 1
// baseline (565.461 us; speedup 1.0000x reference)
//
#include <hip/hip_runtime.h>
#include <math.h>

#define HW 64
#define NCHUNK 8

// 16 doubles = 128 B, loaded wave-uniform (scalar loads) in the raster loop.
struct FaceRasD {
  double invA;
  double dx0, dy0, ax0, ay0;
  double dx1, dy1, ax1, ay1;
  double dx2, dy2, ax2, ay2;
  double z0, z1, z2;
};

__global__ void k_transform(const float* __restrict__ vert,
                            const float* __restrict__ rot,
                            const float* __restrict__ trans,
                            float* __restrict__ vs_cam, int B, int V) {
  int i = blockIdx.x * blockDim.x + threadIdx.x;
  if (i >= B * V) return;
  int b = i / V;
  float x = vert[i * 3 + 0], y = vert[i * 3 + 1], z = vert[i * 3 + 2];
  const float* R = rot + b * 9;
  const float* t = trans + b * 3;
  vs_cam[i * 3 + 0] = ((x * R[0] + y * R[1]) + z * R[2]) + t[0];
  vs_cam[i * 3 + 1] = ((x * R[3] + y * R[4]) + z * R[5]) + t[1];
  vs_cam[i * 3 + 2] = ((x * R[6] + y * R[7]) + z * R[8]) + t[2];
}

__global__ void k_facepre(const float* __restrict__ vs_cam,
                          const int* __restrict__ faces,
                          FaceRasD* __restrict__ fras,
                          float* __restrict__ vnorm,
                          int B, int V, int F) {
  int i = blockIdx.x * blockDim.x + threadIdx.x;
  if (i >= B * F) return;
  int b = i / F, f = i % F;
  int i0 = faces[f * 3 + 0], i1 = faces[f * 3 + 1], i2 = faces[f * 3 + 2];
  const float* c0 = vs_cam + (size_t)(b * V + i0) * 3;
  const float* c1 = vs_cam + (size_t)(b * V + i1) * 3;
  const float* c2 = vs_cam + (size_t)(b * V + i2) * 3;
  float c0x = c0[0], c0y = c0[1], c0z = c0[2];
  float c1x = c1[0], c1y = c1[1], c1z = c1[2];
  float c2x = c2[0], c2y = c2[1], c2z = c2[2];
  // image coords (f32, matches reference vs_img = xy/z)
  float v0x = c0x / c0z, v0y = c0y / c0z;
  float v1x = c1x / c1z, v1y = c1y / c1z;
  float v2x = c2x / c2z, v2y = c2y / c2z;
  // edge deltas in f32 (reference computes (b-a) in f32 before f64 promotion)
  float dx0 = v2x - v1x, dy0 = v2y - v1y;   // edge(v1,v2)
  float dx1 = v0x - v2x, dy1 = v0y - v2y;   // edge(v2,v0)
  float dx2 = v1x - v0x, dy2 = v1y - v0y;   // edge(v0,v1)
  float A = dx2 * (v2y - v0y) - dy2 * (v2x - v0x);  // f32, like reference
  if (fabsf(A) < 1e-8f) A = 1e-8f;                   // signed replacement -> +1e-8
  FaceRasD fr;
  fr.invA = 1.0 / (double)A;
  fr.dx0 = dx0; fr.dy0 = dy0; fr.ax0 = v1x; fr.ay0 = v1y;
  fr.dx1 = dx1; fr.dy1 = dy1; fr.ax1 = v2x; fr.ay1 = v2y;
  fr.dx2 = dx2; fr.dy2 = dy2; fr.ax2 = v0x; fr.ay2 = v0y;
  fr.z0 = c0z; fr.z1 = c1z; fr.z2 = c2z;
  fras[i] = fr;
  // face normal (camera space, f32) scattered to vertex normals
  float e1x = c1x - c0x, e1y = c1y - c0y, e1z = c1z - c0z;
  float e2x = c2x - c0x, e2y = c2y - c0y, e2z = c2z - c0z;
  float nx = e1y * e2z - e1z * e2y;
  float ny = e1z * e2x - e1x * e2z;
  float nz = e1x * e2y - e1y * e2x;
  float* vn0 = vnorm + (size_t)(b * V + i0) * 3;
  float* vn1 = vnorm + (size_t)(b * V + i1) * 3;
  float* vn2 = vnorm + (size_t)(b * V + i2) * 3;
  atomicAdd(vn0 + 0, nx); atomicAdd(vn0 + 1, ny); atomicAdd(vn0 + 2, nz);
  atomicAdd(vn1 + 0, nx); atomicAdd(vn1 + 1, ny); atomicAdd(vn1 + 2, nz);
  atomicAdd(vn2 + 0, nx); atomicAdd(vn2 + 1, ny); atomicAdd(vn2 + 2, nz);
}

__global__ void k_attr(const float* __restrict__ vnorm,
                       const int* __restrict__ faces,
                       const float* __restrict__ attribs,
                       float* __restrict__ attr,
                       int B, int V, int F) {
  int i = blockIdx.x * blockDim.x + threadIdx.x;
  if (i >= B * F) return;
  int b = i / F, f = i % F;
  float* out = attr + (size_t)i * 18;
#pragma unroll
  for (int k = 0; k < 3; ++k) {
    int vid = faces[f * 3 + k];
    const float* n = vnorm + (size_t)(b * V + vid) * 3;
    float nx = n[0], ny = n[1], nz = n[2];
    float nrm = sqrtf(nx * nx + ny * ny + nz * nz) + 1e-10f;  // f32, like ref
    out[k * 6 + 0] = nx / nrm;
    out[k * 6 + 1] = ny / nrm;
    out[k * 6 + 2] = nz / nrm;
    out[k * 6 + 3] = attribs[((size_t)i * 3 + k) * 3 + 0];
    out[k * 6 + 4] = attribs[((size_t)i * 3 + k) * 3 + 1];
    out[k * 6 + 5] = attribs[((size_t)i * 3 + k) * 3 + 2];
  }
}

__global__ __launch_bounds__(256) void k_raster(
    const FaceRasD* __restrict__ fras,
    double* __restrict__ pzmin, int* __restrict__ pbest,
    float* __restrict__ plsum, int F, int FPC) {
  const int PPB = (HW * HW) / 256;          // pixel-blocks per batch image
  int b = blockIdx.x / PPB;                 // wave-uniform -> scalar face loads
  int pix = (blockIdx.x % PPB) * 256 + threadIdx.x;
  int chunk = blockIdx.y;
  int y = pix / HW, x = pix % HW;
  const double step = 2.0 / 63.0;           // np.linspace(-1,1,64) in f64
  double px = (x == HW - 1) ? 1.0 : (x * step - 1.0);
  double py = (y == HW - 1) ? 1.0 : (y * step - 1.0);
  const FaceRasD* __restrict__ fb = fras + (size_t)b * F;
  int f0 = chunk * FPC;
  int f1 = min(F, f0 + FPC);
  double zmin = INFINITY;
  int best = 0;
  float lsum = 0.f;
  for (int f = f0; f < f1; ++f) {
    const FaceRasD fr = fb[f];
    double a0 = fr.dx0 * (py - fr.ay0) - fr.dy0 * (px - fr.ax0);
    double a1 = fr.dx1 * (py - fr.ay1) - fr.dy1 * (px - fr.ax1);
    double a2 = fr.dx2 * (py - fr.ay2) - fr.dy2 * (px - fr.ax2);
    double w0 = a0 * fr.invA, w1 = a1 * fr.invA, w2 = a2 * fr.invA;
    bool inside = (w0 >= 0.0) & (w1 >= 0.0) & (w2 >= 0.0);
    double z = (w0 * fr.z0 + w1 * fr.z1) + w2 * fr.z2;
    if (inside & (z > 0.0) & (z < zmin)) { zmin = z; best = f; }  // strict < : first-occurrence argmin
    double dmin = fmin(fmin(w0, w1), w2);
    float t = fminf(fmaxf((float)(dmin * 100.0), -30.0f), 0.0f);
    float pr = __expf(t);                    // inside => dmin>=0 => t==0 => pr==1 exactly
    lsum += log1pf(-pr * (1.0f - 1e-7f));
  }
  int p = b * (HW * HW) + pix;
  size_t idx = (size_t)p * NCHUNK + chunk;
  pzmin[idx] = zmin;
  pbest[idx] = best;
  plsum[idx] = lsum;
}

__global__ void k_final(const FaceRasD* __restrict__ fras,
                        const float* __restrict__ attr,
                        const double* __restrict__ pzmin,
                        const int* __restrict__ pbest,
                        const float* __restrict__ plsum,
                        float* __restrict__ out, int B, int F) {
  int p = blockIdx.x * blockDim.x + threadIdx.x;
  int P = B * HW * HW;
  if (p >= P) return;
  double zmin = INFINITY;
  int best = 0;
  float lsum = 0.f;
#pragma unroll
  for (int c = 0; c < NCHUNK; ++c) {       // ascending: preserves first-min tiebreak
    size_t idx = (size_t)p * NCHUNK + c;
    double z = pzmin[idx];
    int bi = pbest[idx];
    if (z < zmin) { zmin = z; best = bi; }
    lsum += plsum[idx];
  }
  bool covered = (zmin < 1e300);
  int b = p / (HW * HW);
  int pix = p % (HW * HW);
  int y = pix / HW, x = pix % HW;
  const double step = 2.0 / 63.0;
  double px = (x == HW - 1) ? 1.0 : (x * step - 1.0);
  double py = (y == HW - 1) ? 1.0 : (y * step - 1.0);
  float imn[3] = {0.f, 0.f, 0.f};
  float ima[3] = {0.f, 0.f, 0.f};
  if (covered) {
    const FaceRasD fr = fras[(size_t)b * F + best];
    double a0 = fr.dx0 * (py - fr.ay0) - fr.dy0 * (px - fr.ax0);
    double a1 = fr.dx1 * (py - fr.ay1) - fr.dy1 * (px - fr.ax1);
    double a2 = fr.dx2 * (py - fr.ay2) - fr.dy2 * (px - fr.ax2);
    double w0 = a0 * fr.invA, w1 = a1 * fr.invA, w2 = a2 * fr.invA;
    const float* at = attr + (size_t)(b * F + best) * 18;
    double v[6];
#pragma unroll
    for (int c = 0; c < 6; ++c)
      v[c] = (w0 * (double)at[c] + w1 * (double)at[6 + c]) + w2 * (double)at[12 + c];
    double nn = sqrt(v[0] * v[0] + v[1] * v[1] + v[2] * v[2]) + 1e-10;
    imn[0] = (float)(v[0] / nn);
    imn[1] = (float)(v[1] / nn);
    imn[2] = (float)(v[2] / nn);
    ima[0] = (float)v[3]; ima[1] = (float)v[4]; ima[2] = (float)v[5];
  }
  float improb = 1.0f - __expf(lsum);
  float* o_n = out;                          // imnormal (B,H,W,3)
  float* o_a = out + (size_t)P * 3;          // im_attr  (B,H,W,3)
  float* o_p = out + (size_t)P * 6;          // improb   (B,H,W)
  float* o_i = o_p + P;                      // imdx     (B,H,W) as float
  o_n[(size_t)p * 3 + 0] = imn[0];
  o_n[(size_t)p * 3 + 1] = imn[1];
  o_n[(size_t)p * 3 + 2] = imn[2];
  o_a[(size_t)p * 3 + 0] = ima[0];
  o_a[(size_t)p * 3 + 1] = ima[1];
  o_a[(size_t)p * 3 + 2] = ima[2];
  o_p[p] = improb;
  o_i[p] = covered ? (float)best : -1.0f;
}

extern "C" void kernel_launch(void* const* d_in, const int* in_sizes, int n_in,
                              void* d_out, int out_size, void* d_ws, size_t ws_size,
                              hipStream_t stream) {
  const float* vert    = (const float*)d_in[0];
  const int*   faces   = (const int*)d_in[1];
  const float* attribs = (const float*)d_in[2];
  const float* rot     = (const float*)d_in[3];
  const float* trans   = (const float*)d_in[4];
  int B = in_sizes[4] / 3;
  int V = in_sizes[0] / (3 * B);
  int F = in_sizes[1] / 3;
  int P = B * HW * HW;

  // workspace layout (8-byte aligned blocks first)
  char* w = (char*)d_ws;
  FaceRasD* fras = (FaceRasD*)w; w += sizeof(FaceRasD) * (size_t)B * F;
  double* pzmin  = (double*)w;   w += sizeof(double) * (size_t)P * NCHUNK;
  float* vs_cam  = (float*)w;    w += sizeof(float) * 3 * (size_t)B * V;
  float* vnorm   = (float*)w;    w += sizeof(float) * 3 * (size_t)B * V;
  float* attr    = (float*)w;    w += sizeof(float) * 18 * (size_t)B * F;
  int* pbest     = (int*)w;      w += sizeof(int) * (size_t)P * NCHUNK;
  float* plsum   = (float*)w;    w += sizeof(float) * (size_t)P * NCHUNK;

  hipMemsetAsync(vnorm, 0, sizeof(float) * 3 * (size_t)B * V, stream);
  k_transform<<<(B * V + 255) / 256, 256, 0, stream>>>(vert, rot, trans, vs_cam, B, V);
  k_facepre<<<(B * F + 255) / 256, 256, 0, stream>>>(vs_cam, faces, fras, vnorm, B, V, F);
  k_attr<<<(B * F + 255) / 256, 256, 0, stream>>>(vnorm, faces, attribs, attr, B, V, F);
  int FPC = (F + NCHUNK - 1) / NCHUNK;
  dim3 rg((unsigned)(B * ((HW * HW) / 256)), NCHUNK);
  k_raster<<<rg, 256, 0, stream>>>(fras, pzmin, pbest, plsum, F, FPC);
  k_final<<<(P + 255) / 256, 256, 0, stream>>>(fras, attr, pzmin, pbest, plsum,
                                               (float*)d_out, B, F);
}

// Round 2
// 443.859 us; speedup vs baseline: 1.2740x; 1.2740x over previous
//
#include <hip/hip_runtime.h>
#include <math.h>

#define HW 64
#define NCHUNK 8
#define PPB 16   // 256-thread blocks per 64x64 image

// f32 fast-raster record: 16 floats = 64 B (one s_load_dwordx16)
struct FaceRasF {
  float wx0, wy0, wc0;
  float wx1, wy1, wc1;
  float wx2, wy2, wc2;
  float z0, z1, z2;
  float epsf, epsz;
  float pad0, pad1;
};

__global__ void k_transform(const float* __restrict__ vert,
                            const float* __restrict__ rot,
                            const float* __restrict__ trans,
                            float* __restrict__ vs_cam, int B, int V) {
  int i = blockIdx.x * blockDim.x + threadIdx.x;
  if (i >= B * V) return;
  int b = i / V;
  float x = vert[i * 3 + 0], y = vert[i * 3 + 1], z = vert[i * 3 + 2];
  const float* R = rot + b * 9;
  const float* t = trans + b * 3;
  vs_cam[i * 3 + 0] = ((x * R[0] + y * R[1]) + z * R[2]) + t[0];
  vs_cam[i * 3 + 1] = ((x * R[3] + y * R[4]) + z * R[5]) + t[1];
  vs_cam[i * 3 + 2] = ((x * R[6] + y * R[7]) + z * R[8]) + t[2];
}

__global__ void k_facepre(const float* __restrict__ vs_cam,
                          const int* __restrict__ faces,
                          FaceRasF* __restrict__ frasF,
                          float* __restrict__ vnorm,
                          int B, int V, int F) {
  int i = blockIdx.x * blockDim.x + threadIdx.x;
  if (i >= B * F) return;
  int b = i / F, f = i % F;
  int i0 = faces[f * 3 + 0], i1 = faces[f * 3 + 1], i2 = faces[f * 3 + 2];
  const float* c0 = vs_cam + (size_t)(b * V + i0) * 3;
  const float* c1 = vs_cam + (size_t)(b * V + i1) * 3;
  const float* c2 = vs_cam + (size_t)(b * V + i2) * 3;
  float c0x = c0[0], c0y = c0[1], c0z = c0[2];
  float c1x = c1[0], c1y = c1[1], c1z = c1[2];
  float c2x = c2[0], c2y = c2[1], c2z = c2[2];
  // f32 image coords (matches reference vs_img = xy/z in f32)
  float v0x = c0x / c0z, v0y = c0y / c0z;
  float v1x = c1x / c1z, v1y = c1y / c1z;
  float v2x = c2x / c2z, v2y = c2y / c2z;
  // f32 edge deltas (reference computes these in f32 before f64 promotion)
  float dx0 = v2x - v1x, dy0 = v2y - v1y;   // edge(v1,v2), anchor v1
  float dx1 = v0x - v2x, dy1 = v0y - v2y;   // edge(v2,v0), anchor v2
  float dx2 = v1x - v0x, dy2 = v1y - v0y;   // edge(v0,v1), anchor v0
  float A = dx2 * (v2y - v0y) - dy2 * (v2x - v0x);
  if (fabsf(A) < 1e-8f) A = 1e-8f;
  double invA = 1.0 / (double)A;
  // premultiplied barycentric coefficients: w_e = wx*px + wy*py + wc
  double wx0 = -(double)dy0 * invA, wy0 = (double)dx0 * invA;
  double wc0 = ((double)dy0 * (double)v1x - (double)dx0 * (double)v1y) * invA;
  double wx1 = -(double)dy1 * invA, wy1 = (double)dx1 * invA;
  double wc1 = ((double)dy1 * (double)v2x - (double)dx1 * (double)v2y) * invA;
  double wx2 = -(double)dy2 * invA, wy2 = (double)dx2 * invA;
  double wc2 = ((double)dy2 * (double)v0x - (double)dx2 * (double)v0y) * invA;
  double m0 = fabs(wx0) + fabs(wy0) + fabs(wc0);
  double m1 = fabs(wx1) + fabs(wy1) + fabs(wc1);
  double m2 = fabs(wx2) + fabs(wy2) + fabs(wc2);
  double mm = fmax(fmax(m0, m1), m2);
  float epsf = fmaxf((float)(2e-6 * mm), 1e-6f);  // ~5x over true f32 eval error
  float zs = fabsf(c0z) + fabsf(c1z) + fabsf(c2z);
  float epsz = (epsf + 4e-6f) * zs;
  FaceRasF fr;
  fr.wx0 = (float)wx0; fr.wy0 = (float)wy0; fr.wc0 = (float)wc0;
  fr.wx1 = (float)wx1; fr.wy1 = (float)wy1; fr.wc1 = (float)wc1;
  fr.wx2 = (float)wx2; fr.wy2 = (float)wy2; fr.wc2 = (float)wc2;
  fr.z0 = c0z; fr.z1 = c1z; fr.z2 = c2z;
  fr.epsf = epsf; fr.epsz = epsz; fr.pad0 = 0.f; fr.pad1 = 0.f;
  frasF[i] = fr;
  // face normal -> vertex normal scatter (f32 atomics, matches ref tolerance)
  float e1x = c1x - c0x, e1y = c1y - c0y, e1z = c1z - c0z;
  float e2x = c2x - c0x, e2y = c2y - c0y, e2z = c2z - c0z;
  float nx = e1y * e2z - e1z * e2y;
  float ny = e1z * e2x - e1x * e2z;
  float nz = e1x * e2y - e1y * e2x;
  float* vn0 = vnorm + (size_t)(b * V + i0) * 3;
  float* vn1 = vnorm + (size_t)(b * V + i1) * 3;
  float* vn2 = vnorm + (size_t)(b * V + i2) * 3;
  atomicAdd(vn0 + 0, nx); atomicAdd(vn0 + 1, ny); atomicAdd(vn0 + 2, nz);
  atomicAdd(vn1 + 0, nx); atomicAdd(vn1 + 1, ny); atomicAdd(vn1 + 2, nz);
  atomicAdd(vn2 + 0, nx); atomicAdd(vn2 + 1, ny); atomicAdd(vn2 + 2, nz);
}

__global__ void k_attr(const float* __restrict__ vnorm,
                       const int* __restrict__ faces,
                       const float* __restrict__ attribs,
                       float* __restrict__ attr,
                       int B, int V, int F) {
  int i = blockIdx.x * blockDim.x + threadIdx.x;
  if (i >= B * F) return;
  int b = i / F, f = i % F;
  float* out = attr + (size_t)i * 18;
#pragma unroll
  for (int k = 0; k < 3; ++k) {
    int vid = faces[f * 3 + k];
    const float* n = vnorm + (size_t)(b * V + vid) * 3;
    float nx = n[0], ny = n[1], nz = n[2];
    float nrm = sqrtf(nx * nx + ny * ny + nz * nz) + 1e-10f;
    out[k * 6 + 0] = nx / nrm;
    out[k * 6 + 1] = ny / nrm;
    out[k * 6 + 2] = nz / nrm;
    out[k * 6 + 3] = attribs[((size_t)i * 3 + k) * 3 + 0];
    out[k * 6 + 4] = attribs[((size_t)i * 3 + k) * 3 + 1];
    out[k * 6 + 5] = attribs[((size_t)i * 3 + k) * 3 + 2];
  }
}

// fast f32 screened raster
__global__ __launch_bounds__(256) void k_raster(
    const FaceRasF* __restrict__ frasF,
    float* __restrict__ pz, unsigned* __restrict__ pbv,
    float* __restrict__ pl, float* __restrict__ pe,
    int F, int FPC, int P) {
  int b = blockIdx.x / PPB;
  int pix = (blockIdx.x % PPB) * 256 + threadIdx.x;
  int chunk = blockIdx.y;
  int y = pix >> 6, x = pix & 63;
  const double step = 2.0 / 63.0;
  double pxd = (x == HW - 1) ? 1.0 : (x * step - 1.0);
  double pyd = (y == HW - 1) ? 1.0 : (y * step - 1.0);
  float pxf = (float)pxd, pyf = (float)pyd;
  const FaceRasF* __restrict__ fb = frasF + (size_t)b * F;
  int f0 = chunk * FPC;
  int f1 = min(F, f0 + FPC);
  float zminf = INFINITY;
  float weps = 0.f;
  int best = 0;
  bool flag = false;
  float lsum = 0.f;
  for (int f = f0; f < f1; ++f) {
    const FaceRasF fr = fb[f];
    float w0 = fmaf(fr.wx0, pxf, fmaf(fr.wy0, pyf, fr.wc0));
    float w1 = fmaf(fr.wx1, pxf, fmaf(fr.wy1, pyf, fr.wc1));
    float w2 = fmaf(fr.wx2, pxf, fmaf(fr.wy2, pyf, fr.wc2));
    float dmin = fminf(fminf(w0, w1), w2);
    if (dmin > -0.3f) {
      // clip(dmin/sigma,-30,0): for dmin<=-0.3 term is -exp(-30)~1e-13, skipped
      float t = fminf(fmaxf(dmin * 100.0f, -30.0f), 0.0f);
      float pr = __expf(t);                       // inside -> t=0 -> pr=1 exactly
      lsum += __logf(fmaf(-pr, 0.99999990f, 1.0f));
    }
    if (dmin > -fr.epsf) {
      float z = fmaf(w2, fr.z2, fmaf(w1, fr.z1, w0 * fr.z0));
      bool contend = (z < zminf + fr.epsz + weps) & (z > -fr.epsz);
      flag |= (fabsf(dmin) < fr.epsf) & contend;              // inside-sign ambiguous
      flag |= (dmin >= 0.0f) & (fabsf(z) < fr.epsz);          // z>0 boundary ambiguous
      flag |= (dmin >= 0.0f) & (z > 0.0f) &
              (fabsf(z - zminf) < fr.epsz + weps);            // z-order ambiguous
      if ((dmin >= 0.0f) & (z > 0.0f) & (z < zminf)) {        // strict <: first-occurrence
        zminf = z; best = f; weps = fr.epsz;
      }
    }
  }
  int p = b * (HW * HW) + pix;
  size_t idx = (size_t)chunk * P + p;            // coalesced store/load layout
  pz[idx] = zminf;
  pbv[idx] = (unsigned)best | (flag ? 0x80000000u : 0u);
  pl[idx] = lsum;
  pe[idx] = weps;
}

// exact f64 winner recompute + interpolation + output write (not improb)
__device__ void write_winner(const float* __restrict__ vs_cam,
                             const int* __restrict__ faces,
                             const float* __restrict__ attr,
                             float* __restrict__ out, int P,
                             int b, int V, int F, int pix,
                             int best, bool covered) {
  int p = b * (HW * HW) + pix;
  float imn[3] = {0.f, 0.f, 0.f};
  float ima[3] = {0.f, 0.f, 0.f};
  if (covered) {
    int x = pix & 63, y = pix >> 6;
    const double step = 2.0 / 63.0;
    double px = (x == HW - 1) ? 1.0 : (x * step - 1.0);
    double py = (y == HW - 1) ? 1.0 : (y * step - 1.0);
    int i0 = faces[best * 3 + 0], i1 = faces[best * 3 + 1], i2 = faces[best * 3 + 2];
    const float* c0 = vs_cam + (size_t)(b * V + i0) * 3;
    const float* c1 = vs_cam + (size_t)(b * V + i1) * 3;
    const float* c2 = vs_cam + (size_t)(b * V + i2) * 3;
    float v0x = c0[0] / c0[2], v0y = c0[1] / c0[2];
    float v1x = c1[0] / c1[2], v1y = c1[1] / c1[2];
    float v2x = c2[0] / c2[2], v2y = c2[1] / c2[2];
    float dx0 = v2x - v1x, dy0 = v2y - v1y;
    float dx1 = v0x - v2x, dy1 = v0y - v2y;
    float dx2 = v1x - v0x, dy2 = v1y - v0y;
    float A = dx2 * (v2y - v0y) - dy2 * (v2x - v0x);
    if (fabsf(A) < 1e-8f) A = 1e-8f;
    double invA = 1.0 / (double)A;
    double a0 = (double)dx0 * (py - (double)v1y) - (double)dy0 * (px - (double)v1x);
    double a1 = (double)dx1 * (py - (double)v2y) - (double)dy1 * (px - (double)v2x);
    double a2 = (double)dx2 * (py - (double)v0y) - (double)dy2 * (px - (double)v0x);
    double w0 = a0 * invA, w1 = a1 * invA, w2 = a2 * invA;
    const float* at = attr + (size_t)(b * F + best) * 18;
    double v[6];
#pragma unroll
    for (int c = 0; c < 6; ++c)
      v[c] = (w0 * (double)at[c] + w1 * (double)at[6 + c]) + w2 * (double)at[12 + c];
    double nn = sqrt(v[0] * v[0] + v[1] * v[1] + v[2] * v[2]) + 1e-10;
    imn[0] = (float)(v[0] / nn);
    imn[1] = (float)(v[1] / nn);
    imn[2] = (float)(v[2] / nn);
    ima[0] = (float)v[3]; ima[1] = (float)v[4]; ima[2] = (float)v[5];
  }
  float* o_n = out;
  float* o_a = out + (size_t)P * 3;
  float* o_p = out + (size_t)P * 6;
  float* o_i = o_p + P;
  o_n[(size_t)p * 3 + 0] = imn[0];
  o_n[(size_t)p * 3 + 1] = imn[1];
  o_n[(size_t)p * 3 + 2] = imn[2];
  o_a[(size_t)p * 3 + 0] = ima[0];
  o_a[(size_t)p * 3 + 1] = ima[1];
  o_a[(size_t)p * 3 + 2] = ima[2];
  o_i[p] = covered ? (float)best : -1.0f;
}

__global__ void k_final(const float* __restrict__ vs_cam,
                        const int* __restrict__ faces,
                        const float* __restrict__ attr,
                        const float* __restrict__ pz,
                        const unsigned* __restrict__ pbv,
                        const float* __restrict__ pl,
                        const float* __restrict__ pe,
                        float* __restrict__ out,
                        int* __restrict__ cnt, int* __restrict__ list,
                        int B, int V, int F) {
  int p = blockIdx.x * blockDim.x + threadIdx.x;
  int P = B * HW * HW;
  if (p >= P) return;
  float zmin = INFINITY, weps = 0.f, lsum = 0.f;
  int best = 0;
  bool flag = false;
#pragma unroll
  for (int c = 0; c < NCHUNK; ++c) {   // ascending: preserves first-occurrence argmin
    size_t idx = (size_t)c * P + p;
    float z = pz[idx];
    unsigned pb = pbv[idx];
    float e = pe[idx];
    flag |= (pb >> 31) != 0;
    flag |= fabsf(z - zmin) < (e + weps + 1e-5f);  // cross-chunk near-tie (NaN-safe)
    if (z < zmin) { zmin = z; best = (int)(pb & 0x7fffffffu); weps = e; }
    lsum += pl[idx];
  }
  bool covered = (zmin < 1e38f);
  int b = p >> 12;            // HW*HW = 4096
  int pix = p & 4095;
  write_winner(vs_cam, faces, attr, out, P, b, V, F, pix, best, covered);
  float* o_p = out + (size_t)P * 6;
  o_p[p] = 1.0f - __expf(lsum);
  if (flag) {
    int s = atomicAdd(cnt, 1);
    list[s] = p;
  }
}

// exact f64 re-argmin for flagged pixels: one wave per pixel
__global__ __launch_bounds__(256) void k_repair(
    const float* __restrict__ vs_cam,
    const int* __restrict__ faces,
    const float* __restrict__ attr,
    const int* __restrict__ cnt, const int* __restrict__ list,
    float* __restrict__ out, int B, int V, int F) {
  int P = B * HW * HW;
  int gtid = blockIdx.x * blockDim.x + threadIdx.x;
  int wid = gtid >> 6;
  int lane = threadIdx.x & 63;
  int nwaves = (gridDim.x * blockDim.x) >> 6;
  int n = cnt[0];
  for (int i = wid; i < n; i += nwaves) {
    int p = list[i];
    int b = p >> 12;
    int pix = p & 4095;
    int x = pix & 63, y = pix >> 6;
    const double step = 2.0 / 63.0;
    double px = (x == HW - 1) ? 1.0 : (x * step - 1.0);
    double py = (y == HW - 1) ? 1.0 : (y * step - 1.0);
    double zmin = INFINITY;
    int best = 0x7fffffff;
    for (int f = lane; f < F; f += 64) {
      int i0 = faces[f * 3 + 0], i1 = faces[f * 3 + 1], i2 = faces[f * 3 + 2];
      const float* c0 = vs_cam + (size_t)(b * V + i0) * 3;
      const float* c1 = vs_cam + (size_t)(b * V + i1) * 3;
      const float* c2 = vs_cam + (size_t)(b * V + i2) * 3;
      float c0z = c0[2], c1z = c1[2], c2z = c2[2];
      float v0x = c0[0] / c0z, v0y = c0[1] / c0z;
      float v1x = c1[0] / c1z, v1y = c1[1] / c1z;
      float v2x = c2[0] / c2z, v2y = c2[1] / c2z;
      float dx0 = v2x - v1x, dy0 = v2y - v1y;
      float dx1 = v0x - v2x, dy1 = v0y - v2y;
      float dx2 = v1x - v0x, dy2 = v1y - v0y;
      float A = dx2 * (v2y - v0y) - dy2 * (v2x - v0x);
      if (fabsf(A) < 1e-8f) A = 1e-8f;
      double invA = 1.0 / (double)A;
      double a0 = (double)dx0 * (py - (double)v1y) - (double)dy0 * (px - (double)v1x);
      double a1 = (double)dx1 * (py - (double)v2y) - (double)dy1 * (px - (double)v2x);
      double a2 = (double)dx2 * (py - (double)v0y) - (double)dy2 * (px - (double)v0x);
      double w0 = a0 * invA, w1 = a1 * invA, w2 = a2 * invA;
      bool inside = (w0 >= 0.0) & (w1 >= 0.0) & (w2 >= 0.0);
      double z = (w0 * (double)c0z + w1 * (double)c1z) + w2 * (double)c2z;
      if (inside & (z > 0.0) & (z < zmin)) { zmin = z; best = f; }
    }
    // lexicographic (z, idx) wave reduce -> first-occurrence argmin
    for (int off = 32; off; off >>= 1) {
      double zo = __shfl_down(zmin, off);
      int bo = __shfl_down(best, off);
      if ((zo < zmin) || ((zo == zmin) && (bo < best))) { zmin = zo; best = bo; }
    }
    if (lane == 0) {
      bool covered = (zmin < 1e300);
      write_winner(vs_cam, faces, attr, out, P, b, V, F, pix, best, covered);
    }
  }
}

extern "C" void kernel_launch(void* const* d_in, const int* in_sizes, int n_in,
                              void* d_out, int out_size, void* d_ws, size_t ws_size,
                              hipStream_t stream) {
  const float* vert    = (const float*)d_in[0];
  const int*   faces   = (const int*)d_in[1];
  const float* attribs = (const float*)d_in[2];
  const float* rot     = (const float*)d_in[3];
  const float* trans   = (const float*)d_in[4];
  int B = in_sizes[4] / 3;
  int V = in_sizes[0] / (3 * B);
  int F = in_sizes[1] / 3;
  int P = B * HW * HW;

  char* w = (char*)d_ws;
  FaceRasF* frasF = (FaceRasF*)w; w += sizeof(FaceRasF) * (size_t)B * F;  // 64B-aligned
  float* pz      = (float*)w;     w += sizeof(float) * (size_t)P * NCHUNK;
  unsigned* pbv  = (unsigned*)w;  w += sizeof(unsigned) * (size_t)P * NCHUNK;
  float* pl      = (float*)w;     w += sizeof(float) * (size_t)P * NCHUNK;
  float* pe      = (float*)w;     w += sizeof(float) * (size_t)P * NCHUNK;
  float* vs_cam  = (float*)w;     w += sizeof(float) * 3 * (size_t)B * V;
  float* vnorm   = (float*)w;     w += sizeof(float) * 3 * (size_t)B * V;
  float* attr    = (float*)w;     w += sizeof(float) * 18 * (size_t)B * F;
  int* cnt       = (int*)w;       w += sizeof(int);
  int* list      = (int*)w;       w += sizeof(int) * (size_t)P;

  hipMemsetAsync(vnorm, 0, sizeof(float) * 3 * (size_t)B * V, stream);
  hipMemsetAsync(cnt, 0, sizeof(int), stream);
  k_transform<<<(B * V + 255) / 256, 256, 0, stream>>>(vert, rot, trans, vs_cam, B, V);
  k_facepre<<<(B * F + 255) / 256, 256, 0, stream>>>(vs_cam, faces, frasF, vnorm, B, V, F);
  k_attr<<<(B * F + 255) / 256, 256, 0, stream>>>(vnorm, faces, attribs, attr, B, V, F);
  int FPC = (F + NCHUNK - 1) / NCHUNK;
  dim3 rg((unsigned)(B * PPB), NCHUNK);
  k_raster<<<rg, 256, 0, stream>>>(frasF, pz, pbv, pl, pe, F, FPC, P);
  k_final<<<(P + 255) / 256, 256, 0, stream>>>(vs_cam, faces, attr, pz, pbv, pl, pe,
                                               (float*)d_out, cnt, list, B, V, F);
  k_repair<<<128, 256, 0, stream>>>(vs_cam, faces, attr, cnt, list,
                                    (float*)d_out, B, V, F);
}

// Round 3
// 282.684 us; speedup vs baseline: 2.0003x; 1.5702x over previous
//
#include <hip/hip_runtime.h>
#include <math.h>

#define HW 64
#define PPB 16   // 256-thread blocks per 64x64 image (wave = one row)

// f32 fast-raster record: 16 floats = 64 B (scalar dwordx16 loads)
struct FaceRasF {
  float wx0, wy0, wc0;
  float wx1, wy1, wc1;
  float wx2, wy2, wc2;
  float z0, z1, z2;
  float epsf, epsz;
  float pad0, pad1;
};

__global__ void k_transform(const float* __restrict__ vert,
                            const float* __restrict__ rot,
                            const float* __restrict__ trans,
                            float* __restrict__ vs_cam, int B, int V) {
  int i = blockIdx.x * blockDim.x + threadIdx.x;
  if (i >= B * V) return;
  int b = i / V;
  float x = vert[i * 3 + 0], y = vert[i * 3 + 1], z = vert[i * 3 + 2];
  const float* R = rot + b * 9;
  const float* t = trans + b * 3;
  vs_cam[i * 3 + 0] = ((x * R[0] + y * R[1]) + z * R[2]) + t[0];
  vs_cam[i * 3 + 1] = ((x * R[3] + y * R[4]) + z * R[5]) + t[1];
  vs_cam[i * 3 + 2] = ((x * R[6] + y * R[7]) + z * R[8]) + t[2];
}

__global__ void k_facepre(const float* __restrict__ vs_cam,
                          const int* __restrict__ faces,
                          FaceRasF* __restrict__ frasF,
                          unsigned* __restrict__ yrange,
                          float* __restrict__ vnorm,
                          int B, int V, int F) {
  int i = blockIdx.x * blockDim.x + threadIdx.x;
  if (i >= B * F) return;
  int b = i / F, f = i % F;
  int i0 = faces[f * 3 + 0], i1 = faces[f * 3 + 1], i2 = faces[f * 3 + 2];
  const float* c0 = vs_cam + (size_t)(b * V + i0) * 3;
  const float* c1 = vs_cam + (size_t)(b * V + i1) * 3;
  const float* c2 = vs_cam + (size_t)(b * V + i2) * 3;
  float c0x = c0[0], c0y = c0[1], c0z = c0[2];
  float c1x = c1[0], c1y = c1[1], c1z = c1[2];
  float c2x = c2[0], c2y = c2[1], c2z = c2[2];
  // f32 image coords (matches reference vs_img = xy/z in f32)
  float v0x = c0x / c0z, v0y = c0y / c0z;
  float v1x = c1x / c1z, v1y = c1y / c1z;
  float v2x = c2x / c2z, v2y = c2y / c2z;
  // f32 edge deltas (reference computes these in f32 before f64 promotion)
  float dx0 = v2x - v1x, dy0 = v2y - v1y;   // edge(v1,v2), anchor v1
  float dx1 = v0x - v2x, dy1 = v0y - v2y;   // edge(v2,v0), anchor v2
  float dx2 = v1x - v0x, dy2 = v1y - v0y;   // edge(v0,v1), anchor v0
  float A = dx2 * (v2y - v0y) - dy2 * (v2x - v0x);
  if (fabsf(A) < 1e-8f) A = 1e-8f;
  double invA = 1.0 / (double)A;
  // premultiplied barycentric coefficients: w_e = wx*px + wy*py + wc
  double wx0 = -(double)dy0 * invA, wy0 = (double)dx0 * invA;
  double wc0 = ((double)dy0 * (double)v1x - (double)dx0 * (double)v1y) * invA;
  double wx1 = -(double)dy1 * invA, wy1 = (double)dx1 * invA;
  double wc1 = ((double)dy1 * (double)v2x - (double)dx1 * (double)v2y) * invA;
  double wx2 = -(double)dy2 * invA, wy2 = (double)dx2 * invA;
  double wc2 = ((double)dy2 * (double)v0x - (double)dx2 * (double)v0y) * invA;
  double m0 = fabs(wx0) + fabs(wy0) + fabs(wc0);
  double m1 = fabs(wx1) + fabs(wy1) + fabs(wc1);
  double m2 = fabs(wx2) + fabs(wy2) + fabs(wc2);
  double mm = fmax(fmax(m0, m1), m2);
  float epsf = fmaxf((float)(6e-7 * mm), 3e-7f);  // ~5x over true f32 eval error
  float zs = fabsf(c0z) + fabsf(c1z) + fabsf(c2z);
  float epsz = (epsf + 4e-6f) * zs;
  FaceRasF fr;
  fr.wx0 = (float)wx0; fr.wy0 = (float)wy0; fr.wc0 = (float)wc0;
  fr.wx1 = (float)wx1; fr.wy1 = (float)wy1; fr.wc1 = (float)wc1;
  fr.wx2 = (float)wx2; fr.wy2 = (float)wy2; fr.wc2 = (float)wc2;
  fr.z0 = c0z; fr.z1 = c1z; fr.z2 = c2z;
  fr.epsf = epsf; fr.epsz = epsz; fr.pad0 = 0.f; fr.pad1 = 0.f;
  frasF[i] = fr;
  // conservative y-row interval of the band-dilated triangle.
  // Face touches row y only if for every edge: max_x w_e = wy*y + wc + |wx| >= -band.
  float band = fmaxf(0.302f, 1.5f * epsf);  // >= prob band AND >= z-eps band
  float ylo = -1.01f, yhi = 1.01f;
  bool empty = false;
  float wyA[3] = {fr.wy0, fr.wy1, fr.wy2};
  float gA[3]  = {fr.wc0 + fabsf(fr.wx0) + band,
                  fr.wc1 + fabsf(fr.wx1) + band,
                  fr.wc2 + fabsf(fr.wx2) + band};
#pragma unroll
  for (int e = 0; e < 3; ++e) {
    float wy = wyA[e], g = gA[e];
    if (wy > 1e-30f)       ylo = fmaxf(ylo, -g / wy);
    else if (wy < -1e-30f) yhi = fminf(yhi, -g / wy);
    else                   empty |= (g < 0.f);
    empty |= (g + fabsf(wy) < 0.f);   // box max < -band -> never active
  }
  int r0, r1;
  if (empty || ylo > yhi) { r0 = 1; r1 = 0; }
  else {
    r0 = max(0, (int)floorf((ylo + 1.0f) * 31.5f) - 1);
    r1 = min(63, (int)ceilf((yhi + 1.0f) * 31.5f) + 1);
    if (r0 > r1) { r0 = 1; r1 = 0; }
  }
  yrange[i] = (unsigned)r0 | ((unsigned)r1 << 8);
  // face normal -> vertex normal scatter (f32 atomics)
  float e1x = c1x - c0x, e1y = c1y - c0y, e1z = c1z - c0z;
  float e2x = c2x - c0x, e2y = c2y - c0y, e2z = c2z - c0z;
  float nx = e1y * e2z - e1z * e2y;
  float ny = e1z * e2x - e1x * e2z;
  float nz = e1x * e2y - e1y * e2x;
  float* vn0 = vnorm + (size_t)(b * V + i0) * 3;
  float* vn1 = vnorm + (size_t)(b * V + i1) * 3;
  float* vn2 = vnorm + (size_t)(b * V + i2) * 3;
  atomicAdd(vn0 + 0, nx); atomicAdd(vn0 + 1, ny); atomicAdd(vn0 + 2, nz);
  atomicAdd(vn1 + 0, nx); atomicAdd(vn1 + 1, ny); atomicAdd(vn1 + 2, nz);
  atomicAdd(vn2 + 0, nx); atomicAdd(vn2 + 1, ny); atomicAdd(vn2 + 2, nz);
}

// fast f32 screened raster with per-face row cull
__global__ __launch_bounds__(256) void k_raster(
    const FaceRasF* __restrict__ frasF,
    const unsigned* __restrict__ yrange,
    float* __restrict__ pz, unsigned* __restrict__ pbv,
    float* __restrict__ pl, float* __restrict__ pe,
    int F, int FPC, int P) {
  int b = blockIdx.x / PPB;
  int pix = (blockIdx.x % PPB) * 256 + threadIdx.x;
  int chunk = blockIdx.y;
  int y = pix >> 6, x = pix & 63;
  const double step = 2.0 / 63.0;
  double pxd = (x == HW - 1) ? 1.0 : (x * step - 1.0);
  double pyd = (y == HW - 1) ? 1.0 : (y * step - 1.0);
  float pxf = (float)pxd, pyf = (float)pyd;
  unsigned yw = (unsigned)__builtin_amdgcn_readfirstlane(y);  // wave = one row
  const FaceRasF* __restrict__ fb = frasF + (size_t)b * F;
  const unsigned* __restrict__ yr = yrange + (size_t)b * F;
  int f0 = chunk * FPC;
  int f1 = min(F, f0 + FPC);
  float zminf = INFINITY;
  float weps = 0.f;
  int best = 0;
  bool flag = false;
  float lsum = 0.f;
  for (int f = f0; f < f1; ++f) {
    unsigned r = yr[f];                       // uniform 4B scalar load
    if (yw < (r & 0xffu) || yw > (r >> 8)) continue;  // scalar cull
    const FaceRasF fr = fb[f];
    float w0 = fmaf(fr.wx0, pxf, fmaf(fr.wy0, pyf, fr.wc0));
    float w1 = fmaf(fr.wx1, pxf, fmaf(fr.wy1, pyf, fr.wc1));
    float w2 = fmaf(fr.wx2, pxf, fmaf(fr.wy2, pyf, fr.wc2));
    float dmin = fminf(fminf(w0, w1), w2);
    if (dmin > -0.3f) {
      // clip(dmin/sigma,-30,0): dmin<=-0.3 contributes ~1e-13, skipped
      float t = fminf(fmaxf(dmin * 100.0f, -30.0f), 0.0f);
      float pr = __expf(t);                   // inside -> t=0 -> pr=1 exactly
      lsum += __logf(fmaf(-pr, 0.99999990f, 1.0f));
    }
    if (dmin > -fr.epsf) {
      float z = fmaf(w2, fr.z2, fmaf(w1, fr.z1, w0 * fr.z0));
      bool contend = (z < zminf + fr.epsz + weps) & (z > -fr.epsz);
      flag |= (fabsf(dmin) < fr.epsf) & contend;              // inside-sign ambiguous
      flag |= (dmin >= 0.0f) & (fabsf(z) < fr.epsz);          // z>0 boundary ambiguous
      flag |= (dmin >= 0.0f) & (z > 0.0f) &
              (fabsf(z - zminf) < fr.epsz + weps);            // z-order ambiguous
      if ((dmin >= 0.0f) & (z > 0.0f) & (z < zminf)) {        // strict <: first-occurrence
        zminf = z; best = f; weps = fr.epsz;
      }
    }
  }
  int p = b * (HW * HW) + pix;
  size_t idx = (size_t)chunk * P + p;
  pz[idx] = zminf;
  pbv[idx] = (unsigned)best | (flag ? 0x80000000u : 0u);
  pl[idx] = lsum;
  pe[idx] = weps;
}

// exact f64 winner recompute + gather-interpolate + output write (not improb)
__device__ void write_winner(const float* __restrict__ vs_cam,
                             const int* __restrict__ faces,
                             const float* __restrict__ vnorm,
                             const float* __restrict__ attribs,
                             float* __restrict__ out, int P,
                             int b, int V, int F, int pix,
                             int best, bool covered) {
  int p = b * (HW * HW) + pix;
  float imn[3] = {0.f, 0.f, 0.f};
  float ima[3] = {0.f, 0.f, 0.f};
  if (covered) {
    int x = pix & 63, y = pix >> 6;
    const double step = 2.0 / 63.0;
    double px = (x == HW - 1) ? 1.0 : (x * step - 1.0);
    double py = (y == HW - 1) ? 1.0 : (y * step - 1.0);
    int vid[3] = {faces[best * 3 + 0], faces[best * 3 + 1], faces[best * 3 + 2]};
    const float* c0 = vs_cam + (size_t)(b * V + vid[0]) * 3;
    const float* c1 = vs_cam + (size_t)(b * V + vid[1]) * 3;
    const float* c2 = vs_cam + (size_t)(b * V + vid[2]) * 3;
    float v0x = c0[0] / c0[2], v0y = c0[1] / c0[2];
    float v1x = c1[0] / c1[2], v1y = c1[1] / c1[2];
    float v2x = c2[0] / c2[2], v2y = c2[1] / c2[2];
    float dx0 = v2x - v1x, dy0 = v2y - v1y;
    float dx1 = v0x - v2x, dy1 = v0y - v2y;
    float dx2 = v1x - v0x, dy2 = v1y - v0y;
    float A = dx2 * (v2y - v0y) - dy2 * (v2x - v0x);
    if (fabsf(A) < 1e-8f) A = 1e-8f;
    double invA = 1.0 / (double)A;
    double a0 = (double)dx0 * (py - (double)v1y) - (double)dy0 * (px - (double)v1x);
    double a1 = (double)dx1 * (py - (double)v2y) - (double)dy1 * (px - (double)v2x);
    double a2 = (double)dx2 * (py - (double)v0y) - (double)dy2 * (px - (double)v0x);
    double wk[3] = {a0 * invA, a1 * invA, a2 * invA};
    double v[6] = {0, 0, 0, 0, 0, 0};
#pragma unroll
    for (int k = 0; k < 3; ++k) {
      const float* n = vnorm + (size_t)(b * V + vid[k]) * 3;
      float nx = n[0], ny = n[1], nz = n[2];
      float nrm = sqrtf(nx * nx + ny * ny + nz * nz) + 1e-10f;  // f32, like ref
      const float* at = attribs + (((size_t)(b * F + best)) * 3 + k) * 3;
      v[0] += wk[k] * (double)(nx / nrm);
      v[1] += wk[k] * (double)(ny / nrm);
      v[2] += wk[k] * (double)(nz / nrm);
      v[3] += wk[k] * (double)at[0];
      v[4] += wk[k] * (double)at[1];
      v[5] += wk[k] * (double)at[2];
    }
    double nn = sqrt(v[0] * v[0] + v[1] * v[1] + v[2] * v[2]) + 1e-10;
    imn[0] = (float)(v[0] / nn);
    imn[1] = (float)(v[1] / nn);
    imn[2] = (float)(v[2] / nn);
    ima[0] = (float)v[3]; ima[1] = (float)v[4]; ima[2] = (float)v[5];
  }
  float* o_n = out;
  float* o_a = out + (size_t)P * 3;
  float* o_p = out + (size_t)P * 6;
  float* o_i = o_p + P;
  o_n[(size_t)p * 3 + 0] = imn[0];
  o_n[(size_t)p * 3 + 1] = imn[1];
  o_n[(size_t)p * 3 + 2] = imn[2];
  o_a[(size_t)p * 3 + 0] = ima[0];
  o_a[(size_t)p * 3 + 1] = ima[1];
  o_a[(size_t)p * 3 + 2] = ima[2];
  o_i[p] = covered ? (float)best : -1.0f;
}

__global__ void k_final(const float* __restrict__ vs_cam,
                        const int* __restrict__ faces,
                        const float* __restrict__ vnorm,
                        const float* __restrict__ attribs,
                        const float* __restrict__ pz,
                        const unsigned* __restrict__ pbv,
                        const float* __restrict__ pl,
                        const float* __restrict__ pe,
                        float* __restrict__ out,
                        int* __restrict__ cnt, int* __restrict__ list,
                        int B, int V, int F, int NC) {
  int p = blockIdx.x * blockDim.x + threadIdx.x;
  int P = B * HW * HW;
  if (p >= P) return;
  float zmin = INFINITY, weps = 0.f, lsum = 0.f;
  int best = 0;
  bool flag = false;
  for (int c = 0; c < NC; ++c) {   // ascending: preserves first-occurrence argmin
    size_t idx = (size_t)c * P + p;
    float z = pz[idx];
    unsigned pb = pbv[idx];
    float e = pe[idx];
    flag |= (pb >> 31) != 0;
    flag |= fabsf(z - zmin) < (e + weps + 2e-6f);  // cross-chunk near-tie (NaN-safe)
    if (z < zmin) { zmin = z; best = (int)(pb & 0x7fffffffu); weps = e; }
    lsum += pl[idx];
  }
  bool covered = (zmin < 1e38f);
  int b = p >> 12;            // HW*HW = 4096
  int pix = p & 4095;
  write_winner(vs_cam, faces, vnorm, attribs, out, P, b, V, F, pix, best, covered);
  float* o_p = out + (size_t)P * 6;
  o_p[p] = 1.0f - __expf(lsum);
  if (flag) {
    int s = atomicAdd(cnt, 1);
    list[s] = p;
  }
}

// exact f64 re-argmin for flagged pixels: one wave per pixel
__global__ __launch_bounds__(256) void k_repair(
    const float* __restrict__ vs_cam,
    const int* __restrict__ faces,
    const float* __restrict__ vnorm,
    const float* __restrict__ attribs,
    const int* __restrict__ cnt, const int* __restrict__ list,
    float* __restrict__ out, int B, int V, int F) {
  int P = B * HW * HW;
  int gtid = blockIdx.x * blockDim.x + threadIdx.x;
  int wid = gtid >> 6;
  int lane = threadIdx.x & 63;
  int nwaves = (gridDim.x * blockDim.x) >> 6;
  int n = cnt[0];
  for (int i = wid; i < n; i += nwaves) {
    int p = list[i];
    int b = p >> 12;
    int pix = p & 4095;
    int x = pix & 63, y = pix >> 6;
    const double step = 2.0 / 63.0;
    double px = (x == HW - 1) ? 1.0 : (x * step - 1.0);
    double py = (y == HW - 1) ? 1.0 : (y * step - 1.0);
    double zmin = INFINITY;
    int best = 0x7fffffff;
    for (int f = lane; f < F; f += 64) {
      int i0 = faces[f * 3 + 0], i1 = faces[f * 3 + 1], i2 = faces[f * 3 + 2];
      const float* c0 = vs_cam + (size_t)(b * V + i0) * 3;
      const float* c1 = vs_cam + (size_t)(b * V + i1) * 3;
      const float* c2 = vs_cam + (size_t)(b * V + i2) * 3;
      float c0z = c0[2], c1z = c1[2], c2z = c2[2];
      float v0x = c0[0] / c0z, v0y = c0[1] / c0z;
      float v1x = c1[0] / c1z, v1y = c1[1] / c1z;
      float v2x = c2[0] / c2z, v2y = c2[1] / c2z;
      float dx0 = v2x - v1x, dy0 = v2y - v1y;
      float dx1 = v0x - v2x, dy1 = v0y - v2y;
      float dx2 = v1x - v0x, dy2 = v1y - v0y;
      float A = dx2 * (v2y - v0y) - dy2 * (v2x - v0x);
      if (fabsf(A) < 1e-8f) A = 1e-8f;
      double invA = 1.0 / (double)A;
      double a0 = (double)dx0 * (py - (double)v1y) - (double)dy0 * (px - (double)v1x);
      double a1 = (double)dx1 * (py - (double)v2y) - (double)dy1 * (px - (double)v2x);
      double a2 = (double)dx2 * (py - (double)v0y) - (double)dy2 * (px - (double)v0x);
      double w0 = a0 * invA, w1 = a1 * invA, w2 = a2 * invA;
      bool inside = (w0 >= 0.0) & (w1 >= 0.0) & (w2 >= 0.0);
      double z = (w0 * (double)c0z + w1 * (double)c1z) + w2 * (double)c2z;
      if (inside & (z > 0.0) & (z < zmin)) { zmin = z; best = f; }
    }
    // lexicographic (z, idx) wave reduce -> first-occurrence argmin
    for (int off = 32; off; off >>= 1) {
      double zo = __shfl_down(zmin, off);
      int bo = __shfl_down(best, off);
      if ((zo < zmin) || ((zo == zmin) && (bo < best))) { zmin = zo; best = bo; }
    }
    if (lane == 0) {
      bool covered = (zmin < 1e300);
      write_winner(vs_cam, faces, vnorm, attribs, out, P, b, V, F, pix, best, covered);
    }
  }
}

extern "C" void kernel_launch(void* const* d_in, const int* in_sizes, int n_in,
                              void* d_out, int out_size, void* d_ws, size_t ws_size,
                              hipStream_t stream) {
  const float* vert    = (const float*)d_in[0];
  const int*   faces   = (const int*)d_in[1];
  const float* attribs = (const float*)d_in[2];
  const float* rot     = (const float*)d_in[3];
  const float* trans   = (const float*)d_in[4];
  int B = in_sizes[4] / 3;
  int V = in_sizes[0] / (3 * B);
  int F = in_sizes[1] / 3;
  int P = B * HW * HW;

  // runtime chunk count: as many as ws_size affords (occupancy for k_raster)
  size_t fixedsz = sizeof(FaceRasF) * (size_t)B * F + 4u * (size_t)B * F +
                   24u * (size_t)B * V + 4 + 4u * (size_t)P + 256;
  int NC = 32;
  while (NC > 8 && fixedsz + (size_t)P * 16u * NC > ws_size) NC >>= 1;

  char* w = (char*)d_ws;
  FaceRasF* frasF = (FaceRasF*)w; w += sizeof(FaceRasF) * (size_t)B * F;  // 64B-aligned
  float* pz       = (float*)w;    w += sizeof(float) * (size_t)P * NC;
  unsigned* pbv   = (unsigned*)w; w += sizeof(unsigned) * (size_t)P * NC;
  float* pl       = (float*)w;    w += sizeof(float) * (size_t)P * NC;
  float* pe       = (float*)w;    w += sizeof(float) * (size_t)P * NC;
  unsigned* yrange= (unsigned*)w; w += sizeof(unsigned) * (size_t)B * F;
  float* vs_cam   = (float*)w;    w += sizeof(float) * 3 * (size_t)B * V;
  float* vnorm    = (float*)w;    w += sizeof(float) * 3 * (size_t)B * V;
  int* cnt        = (int*)w;      w += sizeof(int);
  int* list       = (int*)w;      w += sizeof(int) * (size_t)P;

  hipMemsetAsync(vnorm, 0, sizeof(float) * 3 * (size_t)B * V, stream);
  hipMemsetAsync(cnt, 0, sizeof(int), stream);
  k_transform<<<(B * V + 255) / 256, 256, 0, stream>>>(vert, rot, trans, vs_cam, B, V);
  k_facepre<<<(B * F + 255) / 256, 256, 0, stream>>>(vs_cam, faces, frasF, yrange,
                                                     vnorm, B, V, F);
  int FPC = (F + NC - 1) / NC;
  dim3 rg((unsigned)(B * PPB), (unsigned)NC);
  k_raster<<<rg, 256, 0, stream>>>(frasF, yrange, pz, pbv, pl, pe, F, FPC, P);
  k_final<<<(P + 255) / 256, 256, 0, stream>>>(vs_cam, faces, vnorm, attribs,
                                               pz, pbv, pl, pe,
                                               (float*)d_out, cnt, list, B, V, F, NC);
  k_repair<<<256, 256, 0, stream>>>(vs_cam, faces, vnorm, attribs, cnt, list,
                                    (float*)d_out, B, V, F);
}